// Round 5
// baseline (378.416 us; speedup 1.0000x reference)
//
#include <hip/hip_runtime.h>
#include <hip/hip_cooperative_groups.h>
namespace cg = cooperative_groups;

// Problem constants (fixed by setup_inputs).
#define NQ    256       // queries
#define DD    128       // feature dim
#define NK    200000    // stored keys
#define SD    256       // slot dim
#define KTOP  8
#define CAP   1024      // candidate capacity per query (expect ~190 above tau-1)

// Phase A tiling: NCH blocks x 256 thr; each block scores ALL 256 queries
// against its CHK-key chunk. Keys hit HBM exactly once.
#define NCH   500
#define CHK   400               // NCH*CHK == NK
#define KST   80                // keys staged in LDS per iteration
#define NST   (CHK/KST)         // 5 stages
#define KT    (KST/16)          // 5 key-tiles per stage
#define BUFB  (KST*256)         // 20480 B per LDS stage buffer
static_assert(NCH * CHK == NK, "chunking must cover keys");

// Workspace byte offsets (total ~1.07 MB; ws itself is ~819 MB).
#define WS_A    0               // bf16 A-frags: 16 qt x 4 c x 64 lanes x 16B = 64 KB
#define WS_TAUF 65536           // float[256]: tau - margin (phase A filter)
#define WS_TAU  66560           // float[256]: tau (phase B verification)
#define WS_CNT  67584           // int[256]: candidate counts
#define WS_CAND 69632           // int[256][CAP]: candidate key ids (1 MB)

#define NEG_INF (-3.402823466e+38f)

typedef __attribute__((ext_vector_type(8))) short short8;   // 8 bf16 MFMA A/B frag
typedef __attribute__((ext_vector_type(4))) float f32x4;    // MFMA C/D frag

// fp32 -> bf16 round-to-nearest-even.
__device__ __forceinline__ unsigned f2bf(float f) {
    unsigned u = __float_as_uint(f);
    u += 0x7fffu + ((u >> 16) & 1u);
    return u >> 16;
}

// Exact fp32 dot, two 64-dim halves (verified bitwise vs reference: absmax 0).
__device__ __forceinline__ float dot128(const float4* __restrict__ qr,
                                        const float4* __restrict__ kr) {
    float s0 = 0.f, s1 = 0.f;
#pragma unroll
    for (int d = 0; d < 16; ++d) {
        float4 a = qr[d], b = kr[d];
        s0 = fmaf(a.x, b.x, s0); s0 = fmaf(a.y, b.y, s0);
        s0 = fmaf(a.z, b.z, s0); s0 = fmaf(a.w, b.w, s0);
    }
#pragma unroll
    for (int d = 16; d < 32; ++d) {
        float4 a = qr[d], b = kr[d];
        s1 = fmaf(a.x, b.x, s1); s1 = fmaf(a.y, b.y, s1);
        s1 = fmaf(a.z, b.z, s1); s1 = fmaf(a.w, b.w, s1);
    }
    return s0 + s1;
}

template <int T>
__device__ __forceinline__ void topk_insert(float (&vs)[T], int (&vi)[T],
                                            float &vmin, float s, int idx) {
    if (s <= vmin) return;
    bool done = false;
#pragma unroll
    for (int j = 0; j < T; ++j)
        if (!done && vs[j] == vmin) { vs[j] = s; vi[j] = idx; done = true; }
    float m = vs[0];
#pragma unroll
    for (int j = 1; j < T; ++j) m = fminf(m, vs[j]);
    vmin = m;
}

// Tree-merge per-thread top-8 lists -> sort -> slot gather -> write. 256 thr.
__device__ void finalize_write(int q, int t, float (&vs)[KTOP], int (&vi)[KTOP],
                               float vmin, float* ds, int* di,
                               const float* __restrict__ slots,
                               float* __restrict__ out) {
#pragma unroll
    for (int j = 0; j < KTOP; ++j) { ds[t * KTOP + j] = vs[j]; di[t * KTOP + j] = vi[j]; }
    __syncthreads();
    for (int step = 128; step >= 1; step >>= 1) {
        if (t < step) {
            for (int j = 0; j < KTOP; ++j)
                topk_insert<KTOP>(vs, vi, vmin, ds[(t + step) * KTOP + j],
                                  di[(t + step) * KTOP + j]);
#pragma unroll
            for (int j = 0; j < KTOP; ++j) { ds[t * KTOP + j] = vs[j]; di[t * KTOP + j] = vi[j]; }
        }
        __syncthreads();
    }
    if (t == 0) {
        // Sort descending, tie-break lower index (matches lax.top_k).
#pragma unroll
        for (int i = 0; i < KTOP; ++i)
#pragma unroll
            for (int j = 0; j < KTOP - 1 - i; ++j) {
                bool swp = (vs[j + 1] > vs[j]) ||
                           (vs[j + 1] == vs[j] && vi[j + 1] < vi[j]);
                if (swp) {
                    float tf = vs[j]; vs[j] = vs[j + 1]; vs[j + 1] = tf;
                    int   ti = vi[j]; vi[j] = vi[j + 1]; vi[j + 1] = ti;
                }
            }
#pragma unroll
        for (int j = 0; j < KTOP; ++j) { ds[j] = vs[j]; di[j] = vi[j]; }
    }
    __syncthreads();
    const float4* slots4 = (const float4*)slots;
    float4* out4 = (float4*)out;
    for (int f = t; f < KTOP * (SD / 4); f += 256) {
        int j = f >> 6, s4 = f & 63;
        out4[(size_t)q * (KTOP * SD / 4) + f] = slots4[(size_t)di[j] * (SD / 4) + s4];
    }
    if (t < KTOP)
        out[(size_t)NQ * KTOP * SD + q * KTOP + t] = ds[t];
}

// ---- prep body: A-fragments (bf16, MFMA layout), tau, counter zeroing ----
__device__ void prep_body(int b, int t, const float* __restrict__ query,
                          char* __restrict__ ws, char* sm) {
    float* qs = (float*)sm;                         // 16*128 f32 = 8192 B
    float (*nrm)[17] = (float (*)[17])(sm + 8192);  // 1088 B

    const float4* src = (const float4*)(query + (size_t)b * 16 * DD);
    float4* dst = (float4*)qs;
    for (int i = t; i < 512; i += 256) dst[i] = src[i];
    __syncthreads();

    {   // squared-norm partials: row r = t>>4, part p = t&15 (8 elems each)
        int r = t >> 4, p = t & 15;
        float s = 0.f;
#pragma unroll
        for (int j = 0; j < 8; ++j) { float v = qs[r * DD + p * 8 + j]; s = fmaf(v, v, s); }
        nrm[r][p] = s;
    }
    __syncthreads();
    if (t < 16) {
        float s = 0.f;
#pragma unroll
        for (int p = 0; p < 16; ++p) s += nrm[t][p];
        float tau = 3.2f * sqrtf(s);     // scores|q ~ N(0, ||q||^2); E[#>=tau] ~ 137
        ((float*)(ws + WS_TAU))[b * 16 + t]  = tau;
        ((float*)(ws + WS_TAUF))[b * 16 + t] = tau - 1.0f;   // bf16-score margin
    }
    if (b == 0) ((int*)(ws + WS_CNT))[t] = 0;

    {   // A-fragment: unit (qt=b, c=t>>6, lane l=t&63) -> 8 bf16 = 16 B
        int c = t >> 6, l = t & 63, col = l & 15, quad = l >> 4;
        const float* row = qs + col * DD + c * 32 + quad * 8;
        int4 pk;
        pk.x = f2bf(row[0]) | (f2bf(row[1]) << 16);
        pk.y = f2bf(row[2]) | (f2bf(row[3]) << 16);
        pk.z = f2bf(row[4]) | (f2bf(row[5]) << 16);
        pk.w = f2bf(row[6]) | (f2bf(row[7]) << 16);
        ((int4*)(ws + WS_A))[(b * 4 + c) * 64 + l] = pk;
    }
}

// ---- phase A body: MFMA scoring, threshold filter, candidate append ----
__device__ void phaseA_body(int blk, int tid, const float* __restrict__ keys,
                            char* __restrict__ ws, char* sm) {
    const int w = tid >> 6, lane = tid & 63;
    const int col = lane & 15, quad = lane >> 4;
    const int key0 = blk * CHK;

    // A-fragments for 4 query-tiles (queries w*64 .. w*64+63), pinned in VGPRs.
    const short8* wsA = (const short8*)(ws + WS_A);
    short8 A[4][4];
#pragma unroll
    for (int at = 0; at < 4; ++at)
#pragma unroll
        for (int c = 0; c < 4; ++c)
            A[at][c] = wsA[((w * 4 + at) * 4 + c) * 64 + lane];

    // Per-lane filter thresholds for its 16 queries (+ per-at min for fast path).
    const float* tauf = (const float*)(ws + WS_TAUF);
    float tf[4][4], tfmin[4];
#pragma unroll
    for (int at = 0; at < 4; ++at) {
#pragma unroll
        for (int r = 0; r < 4; ++r)
            tf[at][r] = tauf[w * 64 + at * 16 + quad * 4 + r];
        tfmin[at] = fminf(fminf(tf[at][0], tf[at][1]), fminf(tf[at][2], tf[at][3]));
    }

    int* cnt  = (int*)(ws + WS_CNT);
    int* cand = (int*)(ws + WS_CAND);

    // Staging units: u = tid + 256*i (i<5); (tc=u>>6, l=u&63) ->
    // key row (tc>>2)*16 + (l&15), fp32 elems (tc&3)*32 + (l>>4)*8 .. +8.
    float4 rg[5][2];

#define LOAD_STAGE(S)                                                          \
    {                                                                          \
        _Pragma("unroll")                                                      \
        for (int i = 0; i < 5; ++i) {                                          \
            int u = tid + 256 * i, tc = u >> 6, l = u & 63;                    \
            const float* p = keys +                                            \
                (size_t)(key0 + (S) * KST + (tc >> 2) * 16 + (l & 15)) * DD +  \
                (tc & 3) * 32 + (l >> 4) * 8;                                  \
            rg[i][0] = ((const float4*)p)[0];                                  \
            rg[i][1] = ((const float4*)p)[1];                                  \
        }                                                                      \
    }
#define WRITE_STAGE(BUF)                                                       \
    {                                                                          \
        _Pragma("unroll")                                                      \
        for (int i = 0; i < 5; ++i) {                                          \
            int u = tid + 256 * i;                                             \
            int4 pk;                                                           \
            pk.x = f2bf(rg[i][0].x) | (f2bf(rg[i][0].y) << 16);                \
            pk.y = f2bf(rg[i][0].z) | (f2bf(rg[i][0].w) << 16);                \
            pk.z = f2bf(rg[i][1].x) | (f2bf(rg[i][1].y) << 16);                \
            pk.w = f2bf(rg[i][1].z) | (f2bf(rg[i][1].w) << 16);                \
            *(int4*)(sm + (size_t)(BUF) * BUFB + (size_t)u * 16) = pk;         \
        }                                                                      \
    }

    LOAD_STAGE(0);
    WRITE_STAGE(0);
    __syncthreads();

    for (int s = 0; s < NST; ++s) {
        if (s + 1 < NST) LOAD_STAGE(s + 1);      // loads in flight under MFMAs
        const short8* B = (const short8*)(sm + (s & 1) * BUFB);
#pragma unroll
        for (int kt = 0; kt < KT; ++kt) {
            short8 b0 = B[(kt * 4 + 0) * 64 + lane];
            short8 b1 = B[(kt * 4 + 1) * 64 + lane];
            short8 b2 = B[(kt * 4 + 2) * 64 + lane];
            short8 b3 = B[(kt * 4 + 3) * 64 + lane];
            const int kidx = key0 + s * KST + kt * 16 + col;
#pragma unroll
            for (int at = 0; at < 4; ++at) {
                f32x4 acc = {0.f, 0.f, 0.f, 0.f};
                acc = __builtin_amdgcn_mfma_f32_16x16x32_bf16(A[at][0], b0, acc, 0, 0, 0);
                acc = __builtin_amdgcn_mfma_f32_16x16x32_bf16(A[at][1], b1, acc, 0, 0, 0);
                acc = __builtin_amdgcn_mfma_f32_16x16x32_bf16(A[at][2], b2, acc, 0, 0, 0);
                acc = __builtin_amdgcn_mfma_f32_16x16x32_bf16(A[at][3], b3, acc, 0, 0, 0);
                float mx = fmaxf(fmaxf(acc[0], acc[1]), fmaxf(acc[2], acc[3]));
                if (mx > tfmin[at]) {              // rare (~0.3%/lane-group)
#pragma unroll
                    for (int r = 0; r < 4; ++r) {
                        if (acc[r] > tf[at][r]) {
                            int q = w * 64 + at * 16 + quad * 4 + r;
                            int p = atomicAdd(&cnt[q], 1);
                            if (p < CAP) cand[q * CAP + p] = kidx;
                        }
                    }
                }
            }
        }
        if (s + 1 < NST) {
            WRITE_STAGE((s + 1) & 1);            // other buffer: no read conflict
            __syncthreads();
        }
    }
#undef LOAD_STAGE
#undef WRITE_STAGE
}

// ---- phase B body: exact fp32 rescore, verify, top-8, gather (+brute fallback) ----
__device__ void phaseB_body(int q, int t, const float* __restrict__ query,
                            const float* __restrict__ keys,
                            const float* __restrict__ slots,
                            float* __restrict__ out, char* __restrict__ ws,
                            char* sm) {
    float* cs = (float*)sm;             // 4096 B
    int*   ci = (int*)(sm + 4096);      // 4096 B
    float* ds = (float*)(sm + 8192);    // 8192 B
    int*   di = (int*)(sm + 16384);     // 8192 B
    int* nAbove = (int*)(sm + 24576);

    if (t == 0) *nAbove = 0;
    __syncthreads();

    const int m0 = ((const int*)(ws + WS_CNT))[q];
    const int m  = min(m0, CAP);
    const float tq = ((const float*)(ws + WS_TAU))[q];
    const int* cand = (const int*)(ws + WS_CAND) + (size_t)q * CAP;
    const float4* qr = (const float4*)(query + (size_t)q * DD);

    int myAbove = 0;
    for (int c = t; c < m; c += 256) {
        int id = cand[c];
        float s = dot128(qr, (const float4*)(keys + (size_t)id * DD));
        cs[c] = s; ci[c] = id;
        if (s >= tq) ++myAbove;
    }
    if (myAbove) atomicAdd(nAbove, myAbove);
    __syncthreads();

    float vs[KTOP]; int vi[KTOP]; float vmin = NEG_INF;
#pragma unroll
    for (int j = 0; j < KTOP; ++j) { vs[j] = NEG_INF; vi[j] = -1; }

    // Correctness gate: >=8 exact scores >= tau implies every true top-8 key has
    // exact score >= tau, hence bf16 score > tau-1.0, hence is in cand[].
    // Gate failure (P ~ 0) -> inline exact brute force over all keys.
    if (m0 > CAP || *nAbove < KTOP) {
        for (int id = t; id < NK; id += 256) {
            float s = dot128(qr, (const float4*)(keys + (size_t)id * DD));
            topk_insert<KTOP>(vs, vi, vmin, s, id);
        }
    } else {
        for (int c = t; c < m; c += 256)
            topk_insert<KTOP>(vs, vi, vmin, cs[c], ci[c]);
    }

    finalize_write(q, t, vs, vi, vmin, ds, di, slots, out);
}

// ---------------- fused cooperative kernel ----------------
__global__ __launch_bounds__(256, 2)
void fused(const float* __restrict__ query, const float* __restrict__ keys,
           const float* __restrict__ slots, float* __restrict__ out,
           char* __restrict__ ws) {
    __shared__ __align__(16) char sm[2 * BUFB];   // 40960 B, reused per phase
    cg::grid_group g = cg::this_grid();

    if (blockIdx.x < 16) prep_body(blockIdx.x, threadIdx.x, query, ws, sm);
    __threadfence();          // release ws writes (cross-XCD)
    g.sync();
    __threadfence();          // acquire

    phaseA_body(blockIdx.x, threadIdx.x, keys, ws, sm);
    __threadfence();
    g.sync();
    __threadfence();

    if (blockIdx.x < NQ)
        phaseB_body(blockIdx.x, threadIdx.x, query, keys, slots, out, ws, sm);
}

// ---------------- standalone fallback kernels (same bodies) ----------------
__global__ __launch_bounds__(256) void prep_k(const float* __restrict__ query,
                                              char* __restrict__ ws) {
    __shared__ __align__(16) char sm[9280];
    prep_body(blockIdx.x, threadIdx.x, query, ws, sm);
}
__global__ __launch_bounds__(256, 2) void phaseA_k(const float* __restrict__ keys,
                                                   char* __restrict__ ws) {
    __shared__ __align__(16) char sm[2 * BUFB];
    phaseA_body(blockIdx.x, threadIdx.x, keys, ws, sm);
}
__global__ __launch_bounds__(256) void phaseB_k(const float* __restrict__ query,
                                                const float* __restrict__ keys,
                                                const float* __restrict__ slots,
                                                float* __restrict__ out,
                                                char* __restrict__ ws) {
    __shared__ __align__(16) char sm[24704];
    phaseB_body(blockIdx.x, threadIdx.x, query, keys, slots, out, ws, sm);
}

extern "C" void kernel_launch(void* const* d_in, const int* in_sizes, int n_in,
                              void* d_out, int out_size, void* d_ws, size_t ws_size,
                              hipStream_t stream) {
    const float* query = (const float*)d_in[0];
    const float* keys  = (const float*)d_in[1];
    const float* slots = (const float*)d_in[2];
    float* outp = (float*)d_out;
    char*  ws   = (char*)d_ws;
    (void)in_sizes; (void)n_in; (void)out_size; (void)ws_size;

    // Cooperative path requires all NCH blocks co-resident (need >=2 blocks/CU).
    int maxBlk = 0;
    hipError_t qe = hipOccupancyMaxActiveBlocksPerMultiprocessor(
        &maxBlk, (const void*)fused, 256, 0);
    bool coop = (qe == hipSuccess) && ((long)maxBlk * 256 >= NCH);

    if (coop) {
        void* args[5] = {(void*)&query, (void*)&keys, (void*)&slots,
                         (void*)&outp, (void*)&ws};
        hipError_t e = hipLaunchCooperativeKernel((const void*)fused, dim3(NCH),
                                                  dim3(256), args, 0, stream);
        if (e == hipSuccess) return;
    }
    // Fallback: 3-kernel sequence (identical math).
    hipLaunchKernelGGL(prep_k,   dim3(16),  dim3(256), 0, stream, query, ws);
    hipLaunchKernelGGL(phaseA_k, dim3(NCH), dim3(256), 0, stream, keys, ws);
    hipLaunchKernelGGL(phaseB_k, dim3(NQ),  dim3(256), 0, stream, query, keys, slots,
                       outp, ws);
}